// Round 4
// baseline (220.965 us; speedup 1.0000x reference)
//
#include <hip/hip_runtime.h>
#include <math.h>

// N = 20000, E = 640000, IN_DIM = HID = 128, OUT = 64
// Activations bf16 (ushort bits), accumulation fp32 via MFMA 16x16x32.

typedef __attribute__((ext_vector_type(8))) short short8;
typedef __attribute__((ext_vector_type(4))) float floatx4;

__device__ __forceinline__ unsigned short f2b(float f) {
    unsigned u = __float_as_uint(f);
    unsigned r = (u + 0x7fffu + ((u >> 16) & 1u)) >> 16;
    return (unsigned short)r;
}
__device__ __forceinline__ float b2f_lo(unsigned v) {
    return __uint_as_float(v << 16);
}
__device__ __forceinline__ float b2f_hi(unsigned v) {
    return __uint_as_float(v & 0xffff0000u);
}
__device__ __forceinline__ floatx4 MFMA(short8 a, short8 b, floatx4 c) {
    return __builtin_amdgcn_mfma_f32_16x16x32_bf16(a, b, c, 0, 0, 0);
}
__device__ __forceinline__ float gelu_exact(float x) {
    return 0.5f * x * (1.0f + erff(x * 0.70710678118654752440f));
}

#define FRAG(P, ct, ks, lane) (*(const short8*)((P) + (((((ct)*4 + (ks))*64) + (lane)) << 3)))

// ---------------- count fused with weight packing ----------------

__global__ __launch_bounds__(256) void count_pack_kernel(
    const int* __restrict__ eidx, int E, int* __restrict__ cnt,
    const float* Wg, const float* Wsl, const float* Wsr,
    const float* W1, const float* W2, const float* W3,
    unsigned short* Pg, unsigned short* Psl, unsigned short* Psr,
    unsigned short* P1, unsigned short* P2, unsigned short* P3,
    int countBlocks)
{
    if ((int)blockIdx.x < countBlocks) {
        int e = blockIdx.x * 256 + threadIdx.x;
        if (e < E) atomicAdd(&cnt[eidx[E + e]], 1);
        return;
    }
    int t = (blockIdx.x - countBlocks) * 256 + threadIdx.x;
    const float* W; unsigned short* P; int NC = 128; int base;
    if (t < 2048)       { W = Wg;  P = Pg;  base = t; }
    else if (t < 4096)  { W = Wsl; P = Psl; base = t - 2048; }
    else if (t < 6144)  { W = Wsr; P = Psr; base = t - 4096; }
    else if (t < 8192)  { W = W1;  P = P1;  base = t - 6144; }
    else if (t < 10240) { W = W2;  P = P2;  base = t - 8192; }
    else if (t < 11264) { W = W3;  P = P3;  base = t - 10240; NC = 64; }
    else return;
    int l  = base & 63;
    int ks = (base >> 6) & 3;
    int ct = base >> 8;
    int n  = ct * 16 + (l & 15);
    int k0 = ks * 32 + ((l >> 4) << 3);
    short8 v;
    #pragma unroll
    for (int j = 0; j < 8; j++) v[j] = (short)f2b(W[(size_t)(k0 + j) * NC + n]);
    *(short8*)(P + ((size_t)base << 3)) = v;
}

// -------- scan: absolute prefix via decoupled lookback (20 blocks, co-resident)

__global__ __launch_bounds__(256) void scan_kernel(
    const int* __restrict__ cnt, int N,
    int* __restrict__ row_ptr, int* __restrict__ wptr, float* __restrict__ dinv,
    int* __restrict__ gflags, int* __restrict__ gsums)
{
    __shared__ int sh[256];
    __shared__ int s_off;
    int b = blockIdx.x, tid = threadIdx.x;
    int i0 = b * 1024 + tid * 4;
    int v0 = (i0 + 0 < N) ? cnt[i0 + 0] : 0;
    int v1 = (i0 + 1 < N) ? cnt[i0 + 1] : 0;
    int v2 = (i0 + 2 < N) ? cnt[i0 + 2] : 0;
    int v3 = (i0 + 3 < N) ? cnt[i0 + 3] : 0;
    int tot = v0 + v1 + v2 + v3;
    sh[tid] = tot;
    __syncthreads();
    for (int off = 1; off < 256; off <<= 1) {
        int t = (tid >= off) ? sh[tid - off] : 0;
        __syncthreads();
        sh[tid] += t;
        __syncthreads();
    }
    if (tid == 255) {  // publish block total
        gsums[b] = sh[255];
        __hip_atomic_store(&gflags[b], 1, __ATOMIC_RELEASE, __HIP_MEMORY_SCOPE_AGENT);
    }
    if (tid == 0) {    // lookback over predecessors
        int off = 0;
        for (int j = 0; j < b; j++) {
            while (__hip_atomic_load(&gflags[j], __ATOMIC_ACQUIRE,
                                     __HIP_MEMORY_SCOPE_AGENT) == 0) {}
            off += gsums[j];
        }
        s_off = off;
    }
    __syncthreads();
    int excl = s_off + sh[tid] - tot;
    if (i0 + 0 < N) { row_ptr[i0 + 0] = excl;                wptr[i0 + 0] = excl;                dinv[i0 + 0] = rsqrtf((float)(v0 + 1)); }
    if (i0 + 1 < N) { row_ptr[i0 + 1] = excl + v0;           wptr[i0 + 1] = excl + v0;           dinv[i0 + 1] = rsqrtf((float)(v1 + 1)); }
    if (i0 + 2 < N) { row_ptr[i0 + 2] = excl + v0 + v1;      wptr[i0 + 2] = excl + v0 + v1;      dinv[i0 + 2] = rsqrtf((float)(v2 + 1)); }
    if (i0 + 3 < N) { row_ptr[i0 + 3] = excl + v0 + v1 + v2; wptr[i0 + 3] = excl + v0 + v1 + v2; dinv[i0 + 3] = rsqrtf((float)(v3 + 1)); }
    if (b == (int)gridDim.x - 1 && tid == 255) row_ptr[N] = s_off + sh[255];
}

// ------- fill (XCD-partitioned scatter) + GCN GEMM (xs pre-scaled by dinv) ---

__global__ __launch_bounds__(256) void fill_gemm_kernel(
    const int* __restrict__ eidx, int E, int N,
    int* __restrict__ wptr, int* __restrict__ col,
    const float* __restrict__ feat, const float* __restrict__ dinv,
    const unsigned short* __restrict__ Pg, unsigned short* __restrict__ xs,
    int M, int fillBlocks, int PS)
{
    if ((int)blockIdx.x < fillBlocks) {
        // blockIdx % 8 -> XCD round-robin heuristic: partition p's col/wptr
        // lines are dirtied by one XCD only (kills cross-XCD writebacks).
        int p = blockIdx.x & 7;
        int chunk = blockIdx.x >> 3;
        int dlo = p * PS;
        int dhi = dlo + PS; if (dhi > N) dhi = N;
        #pragma unroll
        for (int it = 0; it < 8; it++) {
            int e = (chunk * 8 + it) * 256 + threadIdx.x;
            if (e < E) {
                int d = eidx[E + e];
                if (d >= dlo && d < dhi) {
                    int pos = atomicAdd(&wptr[d], 1);
                    col[pos] = eidx[e];
                }
            }
        }
        return;
    }
    // GCN GEMM: wave computes 16 rows x 64 cols of xs = bf16(dinv .* (feat @ Wg))
    int bid = blockIdx.x - fillBlocks;
    int w = bid * 4 + (threadIdx.x >> 6);
    if (w >= (M / 16) * 2) return;
    int lane = threadIdx.x & 63;
    int m = lane & 15, quad = lane >> 4;
    int rt = w >> 1, ch = w & 1;
    const float* arow = feat + (size_t)(rt * 16 + m) * 128;
    short8 a[4];
    #pragma unroll
    for (int ks = 0; ks < 4; ks++) {
        float4 f0 = *(const float4*)(arow + ks * 32 + quad * 8);
        float4 f1 = *(const float4*)(arow + ks * 32 + quad * 8 + 4);
        short8 s;
        s[0] = (short)f2b(f0.x); s[1] = (short)f2b(f0.y);
        s[2] = (short)f2b(f0.z); s[3] = (short)f2b(f0.w);
        s[4] = (short)f2b(f1.x); s[5] = (short)f2b(f1.y);
        s[6] = (short)f2b(f1.z); s[7] = (short)f2b(f1.w);
        a[ks] = s;
    }
    float dvr[4];
    #pragma unroll
    for (int reg = 0; reg < 4; reg++) dvr[reg] = dinv[rt * 16 + quad * 4 + reg];
    #pragma unroll
    for (int ct = 0; ct < 4; ct++) {
        floatx4 acc = {0.f, 0.f, 0.f, 0.f};
        #pragma unroll
        for (int ks = 0; ks < 4; ks++)
            acc = MFMA(a[ks], FRAG(Pg, ch * 4 + ct, ks, lane), acc);
        #pragma unroll
        for (int reg = 0; reg < 4; reg++)
            xs[(size_t)(rt * 16 + quad * 4 + reg) * 128 + (ch * 4 + ct) * 16 + m] =
                f2b(acc[reg] * dvr[reg]);
    }
}

// ---------------- aggregation: 16 lanes/row, broadcast col loads, no shfl ----
// GCN:  h1[d] = relu(dinv[d]*(sum_s xs'[s] + xs'[d]) + b)   (xs' pre-scaled)
// SAGE: mean[d] = (1/max(deg,1)) * sum_s h1[s]

#define ACCUM(q)                                   \
    acc[0] += b2f_lo((q).x); acc[1] += b2f_hi((q).x); \
    acc[2] += b2f_lo((q).y); acc[3] += b2f_hi((q).y); \
    acc[4] += b2f_lo((q).z); acc[5] += b2f_hi((q).z); \
    acc[6] += b2f_lo((q).w); acc[7] += b2f_hi((q).w);

template<bool GCN>
__global__ __launch_bounds__(256) void agg_kernel(
    const unsigned short* __restrict__ X, const int* __restrict__ row_ptr,
    const int* __restrict__ col, const float* __restrict__ dinv,
    const float* __restrict__ bias, unsigned short* __restrict__ Y, int N)
{
    int w = (int)((blockIdx.x * 256 + threadIdx.x) >> 6);
    if (w >= N) return;
    int lane = threadIdx.x & 63;
    int g = lane >> 4, t = lane & 15;
    const uint4* Xq = (const uint4*)X;
    int beg = row_ptr[w], end = row_ptr[w + 1];
    int deg = end - beg;

    float acc[8] = {0.f, 0.f, 0.f, 0.f, 0.f, 0.f, 0.f, 0.f};
    int jb = beg;
    for (; jb + 16 <= end; jb += 16) {
        int s0 = col[jb + g];
        int s1 = col[jb + g + 4];
        int s2 = col[jb + g + 8];
        int s3 = col[jb + g + 12];
        uint4 q0 = Xq[(size_t)s0 * 16 + t];
        uint4 q1 = Xq[(size_t)s1 * 16 + t];
        uint4 q2 = Xq[(size_t)s2 * 16 + t];
        uint4 q3 = Xq[(size_t)s3 * 16 + t];
        ACCUM(q0) ACCUM(q1) ACCUM(q2) ACCUM(q3)
    }
    for (; jb < end; jb += 4) {
        int j = jb + g;
        if (j < end) {
            int s = col[j];
            uint4 q = Xq[(size_t)s * 16 + t];
            ACCUM(q)
        }
    }
    #pragma unroll
    for (int i = 0; i < 8; i++) {
        acc[i] += __shfl_xor(acc[i], 16);
        acc[i] += __shfl_xor(acc[i], 32);
    }
    if (g == 0) {
        float out[8];
        if (GCN) {
            uint4 q = Xq[(size_t)w * 16 + t];  // self loop (pre-scaled row)
            ACCUM(q)
            float dw = dinv[w];
            float4 b0 = *(const float4*)(bias + t * 8);
            float4 b1 = *(const float4*)(bias + t * 8 + 4);
            out[0] = fmaxf(fmaf(acc[0], dw, b0.x), 0.f);
            out[1] = fmaxf(fmaf(acc[1], dw, b0.y), 0.f);
            out[2] = fmaxf(fmaf(acc[2], dw, b0.z), 0.f);
            out[3] = fmaxf(fmaf(acc[3], dw, b0.w), 0.f);
            out[4] = fmaxf(fmaf(acc[4], dw, b1.x), 0.f);
            out[5] = fmaxf(fmaf(acc[5], dw, b1.y), 0.f);
            out[6] = fmaxf(fmaf(acc[6], dw, b1.z), 0.f);
            out[7] = fmaxf(fmaf(acc[7], dw, b1.w), 0.f);
        } else {
            float rc = 1.0f / (float)(deg > 0 ? deg : 1);
            #pragma unroll
            for (int i = 0; i < 8; i++) out[i] = acc[i] * rc;
        }
        uint4 r;
        r.x = (unsigned)f2b(out[0]) | ((unsigned)f2b(out[1]) << 16);
        r.y = (unsigned)f2b(out[2]) | ((unsigned)f2b(out[3]) << 16);
        r.z = (unsigned)f2b(out[4]) | ((unsigned)f2b(out[5]) << 16);
        r.w = (unsigned)f2b(out[6]) | ((unsigned)f2b(out[7]) << 16);
        ((uint4*)Y)[(size_t)w * 16 + t] = r;
    }
}

// ---------------- fused SAGE + policy MLP + value head ----------------

__global__ __launch_bounds__(256) void sage_mlp_kernel(
    const unsigned short* __restrict__ mean, const unsigned short* __restrict__ h1,
    const unsigned short* __restrict__ Psl, const unsigned short* __restrict__ Psr,
    const float* __restrict__ bsl,
    const unsigned short* __restrict__ P1, const float* __restrict__ b1,
    const unsigned short* __restrict__ P2, const float* __restrict__ b2,
    const unsigned short* __restrict__ P3, const float* __restrict__ b3,
    const float* __restrict__ Wv, const float* __restrict__ bv,
    float* __restrict__ means, float* __restrict__ values, int M)
{
    __shared__ unsigned short z[4][16 * 136];
    int widx = threadIdx.x >> 6, lane = threadIdx.x & 63;
    int w = blockIdx.x * 4 + widx;
    if (w >= M / 16) return;
    int m = lane & 15, quad = lane >> 4;
    unsigned short* zt = &z[widx][0];
    int r0 = w * 16;

    short8 am[4], ar[4];
    #pragma unroll
    for (int ks = 0; ks < 4; ks++) {
        am[ks] = *(const short8*)(mean + (size_t)(r0 + m) * 128 + ks * 32 + quad * 8);
        ar[ks] = *(const short8*)(h1   + (size_t)(r0 + m) * 128 + ks * 32 + quad * 8);
    }

    float vpart[4] = {0.f, 0.f, 0.f, 0.f};
    #pragma unroll
    for (int ct = 0; ct < 8; ct++) {
        floatx4 acc = {0.f, 0.f, 0.f, 0.f};
        #pragma unroll
        for (int ks = 0; ks < 4; ks++) acc = MFMA(am[ks], FRAG(Psl, ct, ks, lane), acc);
        #pragma unroll
        for (int ks = 0; ks < 4; ks++) acc = MFMA(ar[ks], FRAG(Psr, ct, ks, lane), acc);
        float bb = bsl[ct * 16 + m];
        float wv = Wv[ct * 16 + m];
        #pragma unroll
        for (int reg = 0; reg < 4; reg++) {
            float o = fmaxf(acc[reg] + bb, 0.f);
            vpart[reg] = fmaf(o, wv, vpart[reg]);
            zt[(quad * 4 + reg) * 136 + ct * 16 + m] = f2b(o);
        }
    }
    #pragma unroll
    for (int off = 1; off <= 8; off <<= 1) {
        #pragma unroll
        for (int reg = 0; reg < 4; reg++)
            vpart[reg] += __shfl_xor(vpart[reg], off);
    }
    if (m == 0) {
        float bvv = bv[0];
        #pragma unroll
        for (int reg = 0; reg < 4; reg++)
            values[r0 + quad * 4 + reg] = vpart[reg] + bvv;
    }

    short8 a1[4];
    #pragma unroll
    for (int ks = 0; ks < 4; ks++)
        a1[ks] = *(const short8*)(zt + m * 136 + ks * 32 + quad * 8);

    #pragma unroll
    for (int ct = 0; ct < 8; ct++) {
        floatx4 acc = {0.f, 0.f, 0.f, 0.f};
        #pragma unroll
        for (int ks = 0; ks < 4; ks++) acc = MFMA(a1[ks], FRAG(P1, ct, ks, lane), acc);
        float bb = b1[ct * 16 + m];
        #pragma unroll
        for (int reg = 0; reg < 4; reg++)
            zt[(quad * 4 + reg) * 136 + ct * 16 + m] = f2b(gelu_exact(acc[reg] + bb));
    }
    short8 a2[4];
    #pragma unroll
    for (int ks = 0; ks < 4; ks++)
        a2[ks] = *(const short8*)(zt + m * 136 + ks * 32 + quad * 8);

    #pragma unroll
    for (int ct = 0; ct < 8; ct++) {
        floatx4 acc = {0.f, 0.f, 0.f, 0.f};
        #pragma unroll
        for (int ks = 0; ks < 4; ks++) acc = MFMA(a2[ks], FRAG(P2, ct, ks, lane), acc);
        float bb = b2[ct * 16 + m];
        #pragma unroll
        for (int reg = 0; reg < 4; reg++)
            zt[(quad * 4 + reg) * 136 + ct * 16 + m] = f2b(gelu_exact(acc[reg] + bb));
    }
    short8 a3[4];
    #pragma unroll
    for (int ks = 0; ks < 4; ks++)
        a3[ks] = *(const short8*)(zt + m * 136 + ks * 32 + quad * 8);

    #pragma unroll
    for (int ct = 0; ct < 4; ct++) {
        floatx4 acc = {0.f, 0.f, 0.f, 0.f};
        #pragma unroll
        for (int ks = 0; ks < 4; ks++) acc = MFMA(a3[ks], FRAG(P3, ct, ks, lane), acc);
        float bb = b3[ct * 16 + m];
        #pragma unroll
        for (int reg = 0; reg < 4; reg++)
            means[(size_t)(r0 + quad * 4 + reg) * 64 + ct * 16 + m] = acc[reg] + bb;
    }
}

// ---------------- launch ----------------

extern "C" void kernel_launch(void* const* d_in, const int* in_sizes, int n_in,
                              void* d_out, int out_size, void* d_ws, size_t ws_size,
                              hipStream_t stream) {
    const float* feat  = (const float*)d_in[0];
    const int*   eidx  = (const int*)d_in[1];
    const float* W_gcn = (const float*)d_in[2];
    const float* b_gcn = (const float*)d_in[3];
    const float* W_sl  = (const float*)d_in[4];
    const float* b_sl  = (const float*)d_in[5];
    const float* W_sr  = (const float*)d_in[6];
    const float* W1    = (const float*)d_in[7];
    const float* b1    = (const float*)d_in[8];
    const float* W2    = (const float*)d_in[9];
    const float* b2    = (const float*)d_in[10];
    const float* W3    = (const float*)d_in[11];
    const float* b3    = (const float*)d_in[12];
    const float* Wv    = (const float*)d_in[13];
    const float* bv    = (const float*)d_in[14];

    const int N = in_sizes[0] / 128;
    const int E = in_sizes[1] / 2;

    char* ws = (char*)d_ws;
    size_t off = 0;
    auto alloc = [&](size_t bytes) -> void* {
        void* p = ws + off;
        off += (bytes + 255) & ~(size_t)255;
        return p;
    };
    // zero-zone: [gflags(64) | cnt(N)] — one memset covers both
    int*   gflags  = (int*)alloc((size_t)(64 + N) * 4);
    int*   cnt     = gflags + 64;
    size_t zbytes  = (size_t)(64 + N) * 4;
    int*   gsums   = (int*)alloc(64 * 4);
    int*   row_ptr = (int*)alloc((size_t)(N + 1) * 4);
    int*   wptr    = (int*)alloc((size_t)N * 4);
    float* dinv    = (float*)alloc((size_t)N * 4);
    int*   col     = (int*)alloc((size_t)E * 4);
    unsigned short* xs   = (unsigned short*)alloc((size_t)N * 128 * 2);
    unsigned short* h1   = (unsigned short*)alloc((size_t)N * 128 * 2);
    unsigned short* mean = (unsigned short*)alloc((size_t)N * 128 * 2);
    unsigned short* Pg   = (unsigned short*)alloc(2048 * 8 * 2);
    unsigned short* Psl  = (unsigned short*)alloc(2048 * 8 * 2);
    unsigned short* Psr  = (unsigned short*)alloc(2048 * 8 * 2);
    unsigned short* P1   = (unsigned short*)alloc(2048 * 8 * 2);
    unsigned short* P2   = (unsigned short*)alloc(2048 * 8 * 2);
    unsigned short* P3   = (unsigned short*)alloc(1024 * 8 * 2);

    hipMemsetAsync(gflags, 0, zbytes, stream);

    const int countBlocks = (E + 255) / 256;          // 2500
    const int packBlocks  = (11264 + 255) / 256;      // 44
    count_pack_kernel<<<countBlocks + packBlocks, 256, 0, stream>>>(
        eidx, E, cnt, W_gcn, W_sl, W_sr, W1, W2, W3,
        Pg, Psl, Psr, P1, P2, P3, countBlocks);

    const int NB = (N + 1023) / 1024;                 // 20
    scan_kernel<<<NB, 256, 0, stream>>>(cnt, N, row_ptr, wptr, dinv, gflags, gsums);

    const int PS = (N + 7) / 8;                       // 2500 dsts per partition
    const int chunks = (E + 2047) / 2048;             // 313
    const int fillBlocks = chunks * 8;                // 2504
    const int gemmBlocks = ((N / 16) * 2 + 3) / 4;    // 625
    fill_gemm_kernel<<<fillBlocks + gemmBlocks, 256, 0, stream>>>(
        eidx, E, N, wptr, col, feat, dinv, Pg, xs, N, fillBlocks, PS);

    const int agrid = (N + 3) / 4;
    agg_kernel<true><<<agrid, 256, 0, stream>>>(xs, row_ptr, col, dinv, b_gcn, h1, N);
    agg_kernel<false><<<agrid, 256, 0, stream>>>(h1, row_ptr, col, dinv, nullptr, mean, N);

    sage_mlp_kernel<<<(N / 16 + 3) / 4, 256, 0, stream>>>(
        mean, h1, Psl, Psr, b_sl, P1, b1, P2, b2, P3, b3, Wv, bv,
        (float*)d_out, (float*)d_out + (size_t)N * 64, N);
}